// Round 7
// baseline (6785.909 us; speedup 1.0000x reference)
//
#include <hip/hip_runtime.h>
#include <hip/hip_bf16.h>
#include <cstddef>
#include <cstdint>

namespace {

constexpr int B = 2048, T = 128, F = 128, H = 512, L = 8, KW = 10;
constexpr int GATES = 2064;
constexpr int NG = 2048;    // gate columns (permuted)
constexpr int KIN = 640;    // F + H
constexpr int HS = 85;      // H // 6
constexpr int RC = H * KW;  // 5120
constexpr int KS = 8;       // conv split-K slices
constexpr int NROW = 144;   // Bs rows per tile: 128 gates + 16 logit cols
constexpr unsigned NB_STEP = 512;  // 16 nt x 32 mt

typedef __attribute__((ext_vector_type(8))) short short8;
typedef __attribute__((ext_vector_type(4))) float f32x4;

__device__ __forceinline__ float sigmoidf_(float x) { return 1.0f / (1.0f + expf(-x)); }

__device__ __forceinline__ void gl_lds16(const void* g, void* l) {
    __builtin_amdgcn_global_load_lds(
        (const __attribute__((address_space(1))) unsigned int*)g,
        (__attribute__((address_space(3))) unsigned int*)l,
        16, 0, 0);
}

// grid barrier, relaxed agent atomics, bounded spin (no hang on failure).
__device__ __forceinline__ void gridbar(unsigned* cnt, unsigned* gen) {
    __syncthreads();  // all waves' h-stores drained (vmcnt) before arrive
    if (threadIdx.x == 0) {
        unsigned g = __hip_atomic_load(gen, __ATOMIC_RELAXED, __HIP_MEMORY_SCOPE_AGENT);
        if (__hip_atomic_fetch_add(cnt, 1u, __ATOMIC_RELAXED, __HIP_MEMORY_SCOPE_AGENT) == NB_STEP - 1) {
            __hip_atomic_store(cnt, 0u, __ATOMIC_RELAXED, __HIP_MEMORY_SCOPE_AGENT);
            __hip_atomic_fetch_add(gen, 1u, __ATOMIC_RELAXED, __HIP_MEMORY_SCOPE_AGENT);
        } else {
            for (int it = 0; it < (1 << 20); ++it) {
                if (__hip_atomic_load(gen, __ATOMIC_RELAXED, __HIP_MEMORY_SCOPE_AGENT) != g) break;
                __builtin_amdgcn_s_sleep(2);
            }
        }
    }
    __syncthreads();  // full compiler+exec barrier: no h-load hoists above this
}

// ---------- prep ----------
// WgT tile layout: [nt][144 rows][640 k] bf16. Rows 0..127: permuted gate cols
// (col = wc*64+j*16+m16 -> n = 16 + j*512 + nt*32 + wc*16 + m16); rows 128..143:
// the 16 fm/im logit cols (n = row-128), replicated into every tile.
__global__ __launch_bounds__(256) void prep_wgt(
    const float* __restrict__ Wk, const float* __restrict__ Wr,
    __hip_bfloat16* __restrict__ WgT)
{
    __shared__ float tile[64 * 65];
    const int tid = threadIdx.x;
    const int c0 = blockIdx.x * 64, k0 = blockIdx.y * 64;
#pragma unroll
    for (int rep = 0; rep < 16; ++rep) {
        int e = rep * 256 + tid;
        int kl = e >> 6, cl = e & 63;
        int col = c0 + cl;
        int nt = col >> 7, cc = col & 127;
        int n = 16 + ((cc >> 4) & 3) * 512 + nt * 32 + ((cc >> 6) & 1) * 16 + (cc & 15);
        int k = k0 + kl;
        tile[kl * 65 + cl] = (k < F) ? Wk[(size_t)k * GATES + n] : Wr[(size_t)(k - F) * GATES + n];
    }
    __syncthreads();
    const int cl = tid >> 2, q = tid & 3;
    unsigned short buf[16];
#pragma unroll
    for (int i = 0; i < 16; ++i) {
        float f = tile[(q * 16 + i) * 65 + cl];
        __hip_bfloat16 bv = __float2bfloat16(f);
        buf[i] = *(unsigned short*)&bv;
    }
    int col = c0 + cl;
    int nt = col >> 7, rin = col & 127;
    unsigned short* dst = (unsigned short*)WgT + (size_t)nt * NROW * KIN + (size_t)rin * KIN + k0 + q * 16;
    *(short8*)dst = *(short8*)&buf[0];
    *(short8*)(dst + 8) = *(short8*)&buf[8];
}

// logit rows 128..143 of every tile (16 tiles x 16 rows x 640 k)
__global__ void prep_w16rep(const float* __restrict__ Wk, const float* __restrict__ Wr,
                            __hip_bfloat16* __restrict__ WgT)
{
    int idx = blockIdx.x * blockDim.x + threadIdx.x;
    if (idx >= 16 * 16 * KIN) return;
    int nt = idx / (16 * KIN);
    int rem = idx % (16 * KIN);
    int n = rem / KIN, k = rem % KIN;
    float v = (k < F) ? Wk[(size_t)k * GATES + n] : Wr[(size_t)(k - F) * GATES + n];
    WgT[(size_t)nt * NROW * KIN + (size_t)(128 + n) * KIN + k] = __float2bfloat16(v);
}

__global__ void prep_small(const float* __restrict__ Wk, const float* __restrict__ bk,
                           const float* __restrict__ Wr, const float* __restrict__ br,
                           float* __restrict__ biasg, float* __restrict__ wrowg,
                           float* __restrict__ bias16, float* __restrict__ wrow16)
{
    const int total = 2 * NG + 32;
    for (int idx = threadIdx.x; idx < total; idx += 256) {
        if (idx < NG) {
            int col = idx;
            int nt = col >> 7, cc = col & 127;
            int n = 16 + ((cc >> 4) & 3) * 512 + nt * 32 + ((cc >> 6) & 1) * 16 + (cc & 15);
            biasg[col] = bk[n] + br[n];
        } else if (idx < 2 * NG) {
            int col = idx - NG;
            int nt = col >> 7, cc = col & 127;
            int n = 16 + ((cc >> 4) & 3) * 512 + nt * 32 + ((cc >> 6) & 1) * 16 + (cc & 15);
            wrowg[col] = Wk[(size_t)F * GATES + n] + Wr[(size_t)H * GATES + n];
        } else if (idx < 2 * NG + 16) {
            int n = idx - 2 * NG;
            bias16[n] = bk[n] + br[n];
        } else {
            int n = idx - 2 * NG - 16;
            wrow16[n] = Wk[(size_t)F * GATES + n] + Wr[(size_t)H * GATES + n];
        }
    }
}

__global__ void convert_x(const float* __restrict__ x, __hip_bfloat16* __restrict__ xb) {
    int i = blockIdx.x * blockDim.x + threadIdx.x;
    size_t o = (size_t)i * 4;
    if (o >= (size_t)B * T * F) return;
    float4 v = *(const float4*)(x + o);
    xb[o + 0] = __float2bfloat16(v.x);
    xb[o + 1] = __float2bfloat16(v.y);
    xb[o + 2] = __float2bfloat16(v.z);
    xb[o + 3] = __float2bfloat16(v.w);
}

__global__ void prep_convw(const float* __restrict__ conv_w, __hip_bfloat16* __restrict__ CWb) {
    int i = blockIdx.x * blockDim.x + threadIdx.x;
    if (i >= H * RC / 4) return;
    size_t o = (size_t)i * 4;
    float4 v = *(const float4*)(conv_w + o);
    CWb[o + 0] = __float2bfloat16(v.x);
    CWb[o + 1] = __float2bfloat16(v.y);
    CWb[o + 2] = __float2bfloat16(v.z);
    CWb[o + 3] = __float2bfloat16(v.w);
}

// ---------- persistent fused step ----------
struct StepArgs {
    const __hip_bfloat16* xb;
    __hip_bfloat16* h0;
    __hip_bfloat16* h1;
    const __hip_bfloat16* WgT;
    const float* biasg;
    const float* wrowg;
    const float* bias16;
    const float* wrow16;
    const float* tme;
    float* c;
    __hip_bfloat16* tmp_h;
    float* tmp_ds;
    float* dist_out;
    unsigned* bar_cnt;
    unsigned* bar_gen;
};

// grid (16 nt, 32 mt) = 512 blocks, 256 threads, plain launch (2 blocks/CU by
// construction: 26 KB LDS, <=128 VGPR via launch_bounds). M-tile 64, N-tile
// 128(+16 logit cols in Bs), BK 64. h exchanged via agent-scope atomics only.
__global__ __launch_bounds__(256, 2) void persistent_step(StepArgs a)
{
    // staging view: As 64x64 bf16 (8 KB) | Bs 144x64 bf16 (18 KB)
    // epilogue view (aliased, staging dead): logitS 64x17 f32 | fmimS 64x16 f32 | hstage 64x32 bf16
    __shared__ __align__(16) char smem[64 * 64 * 2 + NROW * 64 * 2];  // 26624 B
    unsigned short* As = (unsigned short*)smem;
    unsigned short* Bs = (unsigned short*)(smem + 8192);
    float* logitS = (float*)smem;
    float* fmimS = (float*)(smem + 4352);
    unsigned short* hstageS = (unsigned short*)(smem + 8448);

    const int tid = threadIdx.x;
    const int wave = tid >> 6, lane = tid & 63;
    const int wr = wave >> 1, wc = wave & 1;
    const int quad = lane >> 4, m16 = lane & 15;
    const int nt = blockIdx.x;
    const int m0 = blockIdx.y * 64;
    (void)wave; (void)lane;

    // t-invariant epilogue constants
    const int hcol = nt * 32 + wc * 16 + m16;
    const int lidx = hcol >> 6;
    float bj[4], wj[4];
#pragma unroll
    for (int j = 0; j < 4; ++j) {
        int col = nt * 128 + wc * 64 + j * 16 + m16;
        bj[j] = a.biasg[col];
        wj[j] = a.wrowg[col];
    }
    const unsigned short* wgt_tile = (const unsigned short*)a.WgT + (size_t)nt * NROW * KIN;

#pragma unroll 1
    for (int t = 0; t < T; ++t) {
        const unsigned short* hin = (const unsigned short*)((t & 1) ? a.h1 : a.h0);
        unsigned* hout32 = (unsigned*)((t & 1) ? a.h0 : a.h1);

        f32x4 acc[2][4] = {};
        f32x4 acc16[2] = {};

#pragma unroll 1
        for (int k0 = 0; k0 < KIN; k0 += 64) {
            if (k0 < F) {
                // x part: read-only input, async global->LDS
#pragma unroll
                for (int p = 0; p < 2; ++p) {
                    int o = p * 4096 + tid * 16;
                    int row = o >> 7, slot = (o >> 4) & 7;
                    int kg = k0 + (slot ^ (row & 7)) * 8;
                    gl_lds16(a.xb + ((size_t)(m0 + row) * T + t) * F + kg, smem + o);
                }
            } else {
                // h part: device-coherent agent-scope atomic loads -> ds_write
#pragma unroll
                for (int p = 0; p < 2; ++p) {
                    int o = p * 4096 + tid * 16;
                    int row = o >> 7, slot = (o >> 4) & 7;
                    int kh = (k0 - F) + (slot ^ (row & 7)) * 8;
                    const unsigned long long* src =
                        (const unsigned long long*)(hin + (size_t)(m0 + row) * H + kh);
                    unsigned long long v0 = __hip_atomic_load(src, __ATOMIC_RELAXED, __HIP_MEMORY_SCOPE_AGENT);
                    unsigned long long v1 = __hip_atomic_load(src + 1, __ATOMIC_RELAXED, __HIP_MEMORY_SCOPE_AGENT);
                    *(unsigned long long*)(smem + o) = v0;
                    *(unsigned long long*)(smem + o + 8) = v1;
                }
            }
            // B tile: 144 rows x 64 k (gates + logit rows), read-only weights
#pragma unroll
            for (int p = 0; p < 5; ++p) {
                int idx = p * 4096 + tid * 16;
                if (idx < NROW * 128) {
                    int row = idx >> 7, slot = (idx >> 4) & 7;
                    int kg = k0 + (slot ^ (row & 7)) * 8;
                    gl_lds16(wgt_tile + (size_t)row * KIN + kg, (char*)Bs + idx);
                }
            }
            __syncthreads();

#pragma unroll
            for (int c2 = 0; c2 < 2; ++c2) {
                const int k8 = c2 * 4 + quad;
                short8 av[2], bv[4];
#pragma unroll
                for (int i = 0; i < 2; ++i) {
                    int arow = wr * 32 + i * 16 + m16;
                    av[i] = *(const short8*)&As[arow * 64 + (k8 ^ (arow & 7)) * 8];
                }
#pragma unroll
                for (int j = 0; j < 4; ++j) {
                    int brow = wc * 64 + j * 16 + m16;
                    bv[j] = *(const short8*)&Bs[brow * 64 + (k8 ^ (brow & 7)) * 8];
                }
#pragma unroll
                for (int i = 0; i < 2; ++i)
#pragma unroll
                    for (int j = 0; j < 4; ++j)
                        acc[i][j] = __builtin_amdgcn_mfma_f32_16x16x32_bf16(av[i], bv[j], acc[i][j], 0, 0, 0);
                if (wc == 0) {
                    int lrow = 128 + m16;
                    short8 wv = *(const short8*)&Bs[lrow * 64 + (k8 ^ (lrow & 7)) * 8];
                    acc16[0] = __builtin_amdgcn_mfma_f32_16x16x32_bf16(av[0], wv, acc16[0], 0, 0, 0);
                    acc16[1] = __builtin_amdgcn_mfma_f32_16x16x32_bf16(av[1], wv, acc16[1], 0, 0, 0);
                }
            }
            __syncthreads();
        }

        // logits -> LDS (wc==0 waves cover 64 rows x 16 logits)
        if (wc == 0) {
#pragma unroll
            for (int i = 0; i < 2; ++i)
#pragma unroll
                for (int r = 0; r < 4; ++r)
                    logitS[(wr * 32 + i * 16 + quad * 4 + r) * 17 + m16] = acc16[i][r];
        }
        __syncthreads();

        // per-row softmax-cumsum (fm l2r, im r2l), dist
        if (tid < 64) {
            int m = m0 + tid;
            float dt = a.tme[(size_t)m * T + t];
            float z[16];
#pragma unroll
            for (int n = 0; n < 16; ++n) z[n] = logitS[tid * 17 + n] + a.bias16[n] + dt * a.wrow16[n];
            float mx = z[0];
#pragma unroll
            for (int j = 1; j < L; ++j) mx = fmaxf(mx, z[j]);
            float e[L], s = 0.f;
#pragma unroll
            for (int j = 0; j < L; ++j) { e[j] = expf(z[j] - mx); s += e[j]; }
            float run = 0.f, fsum = 0.f;
#pragma unroll
            for (int j = 0; j < L; ++j) { run += e[j]; float fmv = run / s; fmimS[tid * 16 + j] = fmv; fsum += fmv; }
            mx = z[L];
#pragma unroll
            for (int j = 1; j < L; ++j) mx = fmaxf(mx, z[L + j]);
            s = 0.f;
#pragma unroll
            for (int j = 0; j < L; ++j) { e[j] = expf(z[L + j] - mx); s += e[j]; }
            run = 0.f;
#pragma unroll
            for (int j = L - 1; j >= 0; --j) { run += e[j]; fmimS[tid * 16 + 8 + j] = run / s; }
            if (nt == 0) {
                float d = 1.0f - fsum / (float)L;
                a.dist_out[(size_t)t * B + m] = d;
                if (t >= T - KW) a.tmp_ds[(size_t)(t - (T - KW)) * B + m] = d;
            }
        }
        __syncthreads();

        // gates + cell update (c block-private in global/L2); h -> LDS stage
#pragma unroll
        for (int i = 0; i < 2; ++i) {
#pragma unroll
            for (int r = 0; r < 4; ++r) {
                int rl = wr * 32 + i * 16 + quad * 4 + r;
                int m = m0 + rl;
                float dt = a.tme[(size_t)m * T + t];
                float fmv = fmimS[rl * 16 + lidx];
                float imv = fmimS[rl * 16 + 8 + lidx];
                float fg = sigmoidf_(acc[i][0][r] + bj[0] + dt * wj[0]);
                float ig = sigmoidf_(acc[i][1][r] + bj[1] + dt * wj[1]);
                float og = sigmoidf_(acc[i][2][r] + bj[2] + dt * wj[2]);
                float ci = tanhf(acc[i][3][r] + bj[3] + dt * wj[3]);
                float ov = fmv * imv;
                size_t off = (size_t)m * H + hcol;
                float cl = a.c[off];
                float cn = ov * (fg * cl + ig * ci) + (fmv - ov) * cl + (imv - ov) * ci;
                float hn = og * tanhf(cn);
                a.c[off] = cn;
                __hip_bfloat16 hb = __float2bfloat16(hn);
                hstageS[rl * 32 + (wc * 16 + m16)] = *(unsigned short*)&hb;
                if (t >= T - KW) a.tmp_h[((size_t)(t - (T - KW)) * B + m) * H + hcol] = hb;
            }
        }
        __syncthreads();

        // pack h pairs -> agent-scope atomic dword stores (device-coherent)
        {
            const unsigned* hs32 = (const unsigned*)hstageS;
#pragma unroll
            for (int wds = 0; wds < 4; ++wds) {
                int wi = wds * 256 + tid;
                int row = wi >> 4, cp = wi & 15;
                unsigned v = hs32[row * 16 + cp];
                __hip_atomic_store(hout32 + (size_t)(m0 + row) * (H / 2) + nt * 16 + cp, v,
                                   __ATOMIC_RELAXED, __HIP_MEMORY_SCOPE_AGENT);
            }
        }

        if (t != T - 1) gridbar(a.bar_cnt, a.bar_gen);
    }
}

// ---------- post ----------
__global__ __launch_bounds__(128) void post_local(
    const __hip_bfloat16* __restrict__ tmp_h, const float* __restrict__ tmp_dis,
    float* __restrict__ mean_h, __hip_bfloat16* __restrict__ Ahk)
{
    const int b = blockIdx.x;
    const int tid = threadIdx.x;
    __shared__ float ld[KW];
    if (tid == 0) {
        float cd[KW];
        float run = 0.f;
        for (int k = 0; k < KW; ++k) { run += tmp_dis[(size_t)k * B + b]; cd[k] = run; }
        float mx = cd[0];
        for (int k = 1; k < KW; ++k) mx = fmaxf(mx, cd[k]);
        float s = 0.f;
        for (int k = 0; k < KW; ++k) { cd[k] = expf(cd[k] - mx); s += cd[k]; }
        for (int k = 0; k < KW; ++k) ld[k] = cd[k] / s;
    }
    __syncthreads();
    float ldr[KW];
#pragma unroll
    for (int k = 0; k < KW; ++k) ldr[k] = ld[k];
    for (int h = tid; h < H; h += 128) {
        float s = 0.f;
#pragma unroll
        for (int k = 0; k < KW; ++k) {
            float v = __bfloat162float(tmp_h[((size_t)k * B + b) * H + h]) * ldr[k];
            s += v;
            Ahk[(size_t)b * RC + h * KW + k] = __float2bfloat16(v);
        }
        mean_h[(size_t)b * H + h] = s * (1.0f / KW);
    }
}

__global__ void theme1_k(const float* __restrict__ mean_h, const float* __restrict__ Ws,
                         const float* __restrict__ bs, float* __restrict__ t1)
{
    int idx = blockIdx.x * blockDim.x + threadIdx.x;
    if (idx >= B * HS) return;
    int b = idx / HS, j = idx % HS;
    float s = bs[j];
    const float* mh = mean_h + (size_t)b * H;
    for (int h = 0; h < H; ++h) s += mh[h] * Ws[(size_t)h * HS + j];
    t1[idx] = fmaxf(s, 0.f);
}

__global__ void theme2_k(const float* __restrict__ t1, const float* __restrict__ Wrs,
                         const float* __restrict__ brs, float* __restrict__ theme)
{
    int idx = blockIdx.x * blockDim.x + threadIdx.x;
    if (idx >= B * H) return;
    int b = idx / H, o = idx % H;
    float s = brs[o];
    const float* tv = t1 + (size_t)b * HS;
    for (int j = 0; j < HS; ++j) s += tv[j] * Wrs[(size_t)j * H + o];
    theme[idx] = sigmoidf_(s);
}

__global__ __launch_bounds__(256) void conv_split(
    const __hip_bfloat16* __restrict__ Ahk, const __hip_bfloat16* __restrict__ CWb,
    float* __restrict__ Pbuf)
{
    __shared__ __align__(16) unsigned short As2[128 * 64];
    __shared__ __align__(16) unsigned short Bs2[128 * 64];
    const int tid = threadIdx.x;
    const int wave = tid >> 6, lane = tid & 63;
    const int wr = wave >> 1, wc = wave & 1;
    const int quad = lane >> 4, m16 = lane & 15;
    const int n0 = blockIdx.x * 128, m0 = blockIdx.y * 128;
    const int ksb = blockIdx.z * (RC / KS);
    (void)wave; (void)lane;

    f32x4 acc[4][4] = {};
    for (int k0 = 0; k0 < RC / KS; k0 += 64) {
#pragma unroll
        for (int p = 0; p < 4; ++p) {
            int o = p * 4096 + tid * 16;
            int row = o >> 7, slot = (o >> 4) & 7;
            int kg = ksb + k0 + (slot ^ (row & 7)) * 8;
            gl_lds16((const unsigned short*)Ahk + (size_t)(m0 + row) * RC + kg, (char*)As2 + o);
            gl_lds16((const unsigned short*)CWb + (size_t)(n0 + row) * RC + kg, (char*)Bs2 + o);
        }
        __syncthreads();
#pragma unroll
        for (int c2 = 0; c2 < 2; ++c2) {
            const int k8 = c2 * 4 + quad;
            short8 av[4], bv[4];
#pragma unroll
            for (int i = 0; i < 4; ++i) {
                int arow = wr * 64 + i * 16 + m16;
                av[i] = *(const short8*)&As2[arow * 64 + (k8 ^ (arow & 7)) * 8];
            }
#pragma unroll
            for (int j = 0; j < 4; ++j) {
                int brow = wc * 64 + j * 16 + m16;
                bv[j] = *(const short8*)&Bs2[brow * 64 + (k8 ^ (brow & 7)) * 8];
            }
#pragma unroll
            for (int i = 0; i < 4; ++i)
#pragma unroll
                for (int j = 0; j < 4; ++j)
                    acc[i][j] = __builtin_amdgcn_mfma_f32_16x16x32_bf16(av[i], bv[j], acc[i][j], 0, 0, 0);
        }
        __syncthreads();
    }
    float* P = Pbuf + (size_t)blockIdx.z * B * H;
#pragma unroll
    for (int j = 0; j < 4; ++j) {
        const int col = n0 + wc * 64 + j * 16 + m16;
#pragma unroll
        for (int i = 0; i < 4; ++i) {
            const int rb = m0 + wr * 64 + i * 16 + quad * 4;
#pragma unroll
            for (int r = 0; r < 4; ++r)
                P[(size_t)(rb + r) * H + col] = acc[i][j][r];
        }
    }
}

__global__ void conv_reduce(const float* __restrict__ Pbuf, const float* __restrict__ conv_b,
                            const float* __restrict__ theme, float* __restrict__ out0)
{
    int i = blockIdx.x * blockDim.x + threadIdx.x;
    if (i >= B * H) return;
    float s = conv_b[i & (H - 1)];
#pragma unroll
    for (int ks = 0; ks < KS; ++ks) s += Pbuf[(size_t)ks * B * H + i];
    out0[i] = theme[i] * s;
}

} // namespace

extern "C" void kernel_launch(void* const* d_in, const int* in_sizes, int n_in,
                              void* d_out, int out_size, void* d_ws, size_t ws_size,
                              hipStream_t stream)
{
    (void)in_sizes; (void)n_in; (void)out_size; (void)ws_size;
    const float* x      = (const float*)d_in[0];
    const float* tme    = (const float*)d_in[1];
    const float* Wk     = (const float*)d_in[2];
    const float* bk     = (const float*)d_in[3];
    const float* Wr     = (const float*)d_in[4];
    const float* br     = (const float*)d_in[5];
    const float* Ws     = (const float*)d_in[6];
    const float* bs     = (const float*)d_in[7];
    const float* Wrs    = (const float*)d_in[8];
    const float* brs    = (const float*)d_in[9];
    const float* conv_w = (const float*)d_in[10];
    const float* conv_b = (const float*)d_in[11];

    float* out0 = (float*)d_out;
    float* dist_out = out0 + (size_t)B * H;

    // workspace carve (~166 MB)
    char* w = (char*)d_ws;
    __hip_bfloat16* WgT  = (__hip_bfloat16*)w; w += (size_t)16 * NROW * KIN * 2;
    __hip_bfloat16* xb   = (__hip_bfloat16*)w; w += (size_t)B * T * F * 2;
    __hip_bfloat16* CWb  = (__hip_bfloat16*)w; w += (size_t)H * RC * 2;
    __hip_bfloat16* Ahk  = (__hip_bfloat16*)w; w += (size_t)B * RC * 2;
    __hip_bfloat16* hb0  = (__hip_bfloat16*)w; w += (size_t)B * H * 2;
    __hip_bfloat16* hb1  = (__hip_bfloat16*)w; w += (size_t)B * H * 2;
    __hip_bfloat16* tmp_h = (__hip_bfloat16*)w; w += (size_t)KW * B * H * 2;
    float* biasg  = (float*)w; w += (size_t)NG * 4;
    float* wrowg  = (float*)w; w += (size_t)NG * 4;
    float* bias16 = (float*)w; w += 64;
    float* wrow16 = (float*)w; w += 64;
    float* c      = (float*)w; w += (size_t)B * H * 4;
    float* tmp_ds = (float*)w; w += (size_t)KW * B * 4;
    float* mean_h = (float*)w; w += (size_t)B * H * 4;
    float* t1     = (float*)w; w += (size_t)B * HS * 4;
    float* theme  = (float*)w; w += (size_t)B * H * 4;
    float* Pbuf   = (float*)w; w += (size_t)KS * B * H * 4;
    unsigned* bar = (unsigned*)w; w += 128;

    hipMemsetAsync(c, 0, (size_t)B * H * sizeof(float), stream);
    hipMemsetAsync(hb0, 0, (size_t)B * H * sizeof(__hip_bfloat16), stream);
    hipMemsetAsync(bar, 0, 128, stream);

    prep_wgt<<<dim3(NG / 64, KIN / 64), 256, 0, stream>>>(Wk, Wr, WgT);
    prep_w16rep<<<(16 * 16 * KIN + 255) / 256, 256, 0, stream>>>(Wk, Wr, WgT);
    prep_small<<<1, 256, 0, stream>>>(Wk, bk, Wr, br, biasg, wrowg, bias16, wrow16);
    convert_x<<<((B * T * F / 4) + 255) / 256, 256, 0, stream>>>(x, xb);
    prep_convw<<<((H * RC / 4) + 255) / 256, 256, 0, stream>>>(conv_w, CWb);

    {
        StepArgs sa;
        sa.xb = xb; sa.h0 = hb0; sa.h1 = hb1; sa.WgT = WgT;
        sa.biasg = biasg; sa.wrowg = wrowg; sa.bias16 = bias16; sa.wrow16 = wrow16;
        sa.tme = tme; sa.c = c; sa.tmp_h = tmp_h; sa.tmp_ds = tmp_ds; sa.dist_out = dist_out;
        sa.bar_cnt = bar; sa.bar_gen = bar + 16;
        persistent_step<<<dim3(16, 32), 256, 0, stream>>>(sa);
    }

    post_local<<<B, 128, 0, stream>>>(tmp_h, tmp_ds, mean_h, Ahk);
    theme1_k<<<(B * HS + 255) / 256, 256, 0, stream>>>(mean_h, Ws, bs, t1);
    theme2_k<<<(B * H + 255) / 256, 256, 0, stream>>>(t1, Wrs, brs, theme);
    conv_split<<<dim3(H / 128, B / 128, KS), 256, 0, stream>>>(Ahk, CWb, Pbuf);
    conv_reduce<<<(B * H + 255) / 256, 256, 0, stream>>>(Pbuf, conv_b, theme, out0);
}

// Round 8
// 2883.603 us; speedup vs baseline: 2.3533x; 2.3533x over previous
//
#include <hip/hip_runtime.h>
#include <hip/hip_bf16.h>
#include <cstddef>
#include <cstdint>

namespace {

constexpr int B = 2048, T = 128, F = 128, H = 512, L = 8, KW = 10;
constexpr int GATES = 2064;
constexpr int NG = 2048;    // gate columns (permuted)
constexpr int KIN = 640;    // F + H
constexpr int HS = 85;      // H // 6
constexpr int RC = H * KW;  // 5120
constexpr int KS = 8;       // conv split-K slices
constexpr int NROW = 144;   // Bs rows per tile: 128 gates + 16 logit cols

typedef __attribute__((ext_vector_type(8))) short short8;
typedef __attribute__((ext_vector_type(4))) float f32x4;
typedef unsigned long long ull;

__device__ __forceinline__ float sigmoidf_(float x) { return 1.0f / (1.0f + expf(-x)); }

__device__ __forceinline__ void gl_lds16(const void* g, void* l) {
    __builtin_amdgcn_global_load_lds(
        (const __attribute__((address_space(1))) unsigned int*)g,
        (__attribute__((address_space(3))) unsigned int*)l,
        16, 0, 0);
}

__device__ __forceinline__ ull h_atomic_load(const ull* p) {
    return __hip_atomic_load(p, __ATOMIC_RELAXED, __HIP_MEMORY_SCOPE_AGENT);
}

// Hierarchical grid barrier: 32 leaf counters (64B apart, keyed by mt, 16
// arrivals each) -> master (32 arrivals) -> gen. Monotonic, no resets.
// Relaxed agent atomics only (same semantics that passed in R7).
__device__ __forceinline__ void gridbar(unsigned* leaf, unsigned* master,
                                        unsigned* gen, int mt, unsigned t) {
    __syncthreads();  // drains vmcnt: all sc-coherent h-stores complete
    if (threadIdx.x == 0) {
        unsigned old = __hip_atomic_fetch_add(&leaf[mt * 16], 1u,
                                              __ATOMIC_RELAXED, __HIP_MEMORY_SCOPE_AGENT);
        if (((old + 1u) & 15u) == 0u) {
            unsigned mo = __hip_atomic_fetch_add(master, 1u,
                                                 __ATOMIC_RELAXED, __HIP_MEMORY_SCOPE_AGENT);
            if (((mo + 1u) & 31u) == 0u)
                __hip_atomic_fetch_add(gen, 1u, __ATOMIC_RELAXED, __HIP_MEMORY_SCOPE_AGENT);
        }
        for (int it = 0; it < (1 << 22); ++it) {
            if (__hip_atomic_load(gen, __ATOMIC_RELAXED, __HIP_MEMORY_SCOPE_AGENT) > t) break;
            __builtin_amdgcn_s_sleep(4);
        }
    }
    __syncthreads();
}

// ---------- prep ----------
__global__ __launch_bounds__(256) void prep_wgt(
    const float* __restrict__ Wk, const float* __restrict__ Wr,
    __hip_bfloat16* __restrict__ WgT)
{
    __shared__ float tile[64 * 65];
    const int tid = threadIdx.x;
    const int c0 = blockIdx.x * 64, k0 = blockIdx.y * 64;
#pragma unroll
    for (int rep = 0; rep < 16; ++rep) {
        int e = rep * 256 + tid;
        int kl = e >> 6, cl = e & 63;
        int col = c0 + cl;
        int nt = col >> 7, cc = col & 127;
        int n = 16 + ((cc >> 4) & 3) * 512 + nt * 32 + ((cc >> 6) & 1) * 16 + (cc & 15);
        int k = k0 + kl;
        tile[kl * 65 + cl] = (k < F) ? Wk[(size_t)k * GATES + n] : Wr[(size_t)(k - F) * GATES + n];
    }
    __syncthreads();
    const int cl = tid >> 2, q = tid & 3;
    unsigned short buf[16];
#pragma unroll
    for (int i = 0; i < 16; ++i) {
        float f = tile[(q * 16 + i) * 65 + cl];
        __hip_bfloat16 bv = __float2bfloat16(f);
        buf[i] = *(unsigned short*)&bv;
    }
    int col = c0 + cl;
    int nt = col >> 7, rin = col & 127;
    unsigned short* dst = (unsigned short*)WgT + (size_t)nt * NROW * KIN + (size_t)rin * KIN + k0 + q * 16;
    *(short8*)dst = *(short8*)&buf[0];
    *(short8*)(dst + 8) = *(short8*)&buf[8];
}

__global__ void prep_w16rep(const float* __restrict__ Wk, const float* __restrict__ Wr,
                            __hip_bfloat16* __restrict__ WgT)
{
    int idx = blockIdx.x * blockDim.x + threadIdx.x;
    if (idx >= 16 * 16 * KIN) return;
    int nt = idx / (16 * KIN);
    int rem = idx % (16 * KIN);
    int n = rem / KIN, k = rem % KIN;
    float v = (k < F) ? Wk[(size_t)k * GATES + n] : Wr[(size_t)(k - F) * GATES + n];
    WgT[(size_t)nt * NROW * KIN + (size_t)(128 + n) * KIN + k] = __float2bfloat16(v);
}

__global__ void prep_small(const float* __restrict__ Wk, const float* __restrict__ bk,
                           const float* __restrict__ Wr, const float* __restrict__ br,
                           float* __restrict__ biasg, float* __restrict__ wrowg,
                           float* __restrict__ bias16, float* __restrict__ wrow16)
{
    const int total = 2 * NG + 32;
    for (int idx = threadIdx.x; idx < total; idx += 256) {
        if (idx < NG) {
            int col = idx;
            int nt = col >> 7, cc = col & 127;
            int n = 16 + ((cc >> 4) & 3) * 512 + nt * 32 + ((cc >> 6) & 1) * 16 + (cc & 15);
            biasg[col] = bk[n] + br[n];
        } else if (idx < 2 * NG) {
            int col = idx - NG;
            int nt = col >> 7, cc = col & 127;
            int n = 16 + ((cc >> 4) & 3) * 512 + nt * 32 + ((cc >> 6) & 1) * 16 + (cc & 15);
            wrowg[col] = Wk[(size_t)F * GATES + n] + Wr[(size_t)H * GATES + n];
        } else if (idx < 2 * NG + 16) {
            int n = idx - 2 * NG;
            bias16[n] = bk[n] + br[n];
        } else {
            int n = idx - 2 * NG - 16;
            wrow16[n] = Wk[(size_t)F * GATES + n] + Wr[(size_t)H * GATES + n];
        }
    }
}

__global__ void convert_x(const float* __restrict__ x, __hip_bfloat16* __restrict__ xb) {
    int i = blockIdx.x * blockDim.x + threadIdx.x;
    size_t o = (size_t)i * 4;
    if (o >= (size_t)B * T * F) return;
    float4 v = *(const float4*)(x + o);
    xb[o + 0] = __float2bfloat16(v.x);
    xb[o + 1] = __float2bfloat16(v.y);
    xb[o + 2] = __float2bfloat16(v.z);
    xb[o + 3] = __float2bfloat16(v.w);
}

__global__ void prep_convw(const float* __restrict__ conv_w, __hip_bfloat16* __restrict__ CWb) {
    int i = blockIdx.x * blockDim.x + threadIdx.x;
    if (i >= H * RC / 4) return;
    size_t o = (size_t)i * 4;
    float4 v = *(const float4*)(conv_w + o);
    CWb[o + 0] = __float2bfloat16(v.x);
    CWb[o + 1] = __float2bfloat16(v.y);
    CWb[o + 2] = __float2bfloat16(v.z);
    CWb[o + 3] = __float2bfloat16(v.w);
}

// ---------- persistent fused step ----------
struct StepArgs {
    const __hip_bfloat16* xb;
    __hip_bfloat16* h0;
    __hip_bfloat16* h1;
    const __hip_bfloat16* WgT;
    const float* biasg;
    const float* wrowg;
    const float* bias16;
    const float* wrow16;
    const float* tme;
    __hip_bfloat16* tmp_h;
    float* tmp_ds;
    float* dist_out;
    unsigned* bar;  // leaf[32*16] | master @512 | gen @544
};

// 512 blocks (1-D, XCD-swizzled to nt/mt), 256 threads, plain launch.
// 26 KB LDS + <=128 VGPR -> >=2 blocks/CU co-resident by construction.
__global__ __launch_bounds__(256, 2) void persistent_step(StepArgs a)
{
    __shared__ __align__(16) char smem[64 * 64 * 2 + NROW * 64 * 2];  // 26624 B
    unsigned short* As = (unsigned short*)smem;
    unsigned short* Bs = (unsigned short*)(smem + 8192);
    // epilogue aliases (staging dead by then)
    float* logitS = (float*)smem;                          // 64*17*4 = 4352
    float* fmimS = (float*)(smem + 4352);                  // 64*16*4 = 4096
    unsigned short* hstageS = (unsigned short*)(smem + 8448);  // 64*32*2 = 4096
    float* dts = (float*)(smem + 12544);                   // 64*4

    const int tid = threadIdx.x;
    const int wave = tid >> 6;
    const int wr = wave >> 1, wc = wave & 1;
    const int quad = (tid & 63) >> 4, m16 = tid & 15;
    // XCD swizzle: consecutive blockIdx round-robin XCDs (heuristic); blocks
    // sharing a weight tile (same nt) land on few XCDs -> tile stays L2-hot.
    const int l = blockIdx.x;
    const int nt = (l & 7) * 2 + ((l >> 3) & 1);
    const int mt = l >> 4;
    const int m0 = mt * 64;

    unsigned* leaf = a.bar;
    unsigned* master = a.bar + 512;
    unsigned* genp = a.bar + 544;

    // per-thread staging geometry (two 16B chunks cover As 8 KB)
    const int o0 = tid * 16, o1 = 4096 + tid * 16;
    const int row0 = o0 >> 7, row1 = o1 >> 7;
    const int sl0 = (((o0 >> 4) & 7) ^ (row0 & 7)) * 8;
    const int sl1 = (((o1 >> 4) & 7) ^ (row1 & 7)) * 8;
    const size_t hoff0 = (size_t)(m0 + row0) * H + sl0;
    const size_t hoff1 = (size_t)(m0 + row1) * H + sl1;

    // t-invariant epilogue constants
    const int hcol = nt * 32 + wc * 16 + m16;
    const int lidx = hcol >> 6;
    float bj[4], wj[4];
#pragma unroll
    for (int j = 0; j < 4; ++j) {
        int col = nt * 128 + wc * 64 + j * 16 + m16;
        bj[j] = a.biasg[col];
        wj[j] = a.wrowg[col];
    }
    const unsigned short* wgt_tile = (const unsigned short*)a.WgT + (size_t)nt * NROW * KIN;

    float creg[2][4] = {};  // cell state slice, register-resident across all t

#pragma unroll 1
    for (int t = 0; t < T; ++t) {
        const unsigned short* hin = (const unsigned short*)((t & 1) ? a.h1 : a.h0);
        unsigned* hout32 = (unsigned*)((t & 1) ? a.h0 : a.h1);

        f32x4 acc[2][4] = {};
        f32x4 acc16[2] = {};

        // prefetch first h k-iter (in flight across both x iters)
        ull r0, r1, r2, r3;
        {
            const ull* s0 = (const ull*)(hin + hoff0);
            const ull* s1 = (const ull*)(hin + hoff1);
            r0 = h_atomic_load(s0); r1 = h_atomic_load(s0 + 1);
            r2 = h_atomic_load(s1); r3 = h_atomic_load(s1 + 1);
        }

#pragma unroll 1
        for (int ki = 0; ki < 10; ++ki) {
            const int k0 = ki * 64;
            if (ki < 2) {
                gl_lds16(a.xb + ((size_t)(m0 + row0) * T + t) * F + k0 + sl0, smem + o0);
                gl_lds16(a.xb + ((size_t)(m0 + row1) * T + t) * F + k0 + sl1, smem + o1);
            } else {
                // write prefetched h, then issue next iter's loads (overlap w/ Bs DMA)
                *(ull*)(smem + o0) = r0; *(ull*)(smem + o0 + 8) = r1;
                *(ull*)(smem + o1) = r2; *(ull*)(smem + o1 + 8) = r3;
                if (ki < 9) {
                    const int kh = (ki - 1) * 64;
                    const ull* s0 = (const ull*)(hin + hoff0 + kh);
                    const ull* s1 = (const ull*)(hin + hoff1 + kh);
                    r0 = h_atomic_load(s0); r1 = h_atomic_load(s0 + 1);
                    r2 = h_atomic_load(s1); r3 = h_atomic_load(s1 + 1);
                }
            }
            // B tile: 144 rows x 64 k
#pragma unroll
            for (int p = 0; p < 5; ++p) {
                int idx = p * 4096 + tid * 16;
                if (idx < NROW * 128) {
                    int row = idx >> 7, slot = (idx >> 4) & 7;
                    int kg = k0 + (slot ^ (row & 7)) * 8;
                    gl_lds16(wgt_tile + (size_t)row * KIN + kg, (char*)Bs + idx);
                }
            }
            __syncthreads();

#pragma unroll
            for (int c2 = 0; c2 < 2; ++c2) {
                const int k8 = c2 * 4 + quad;
                short8 av[2], bv[4];
#pragma unroll
                for (int i = 0; i < 2; ++i) {
                    int arow = wr * 32 + i * 16 + m16;
                    av[i] = *(const short8*)&As[arow * 64 + (k8 ^ (arow & 7)) * 8];
                }
#pragma unroll
                for (int j = 0; j < 4; ++j) {
                    int brow = wc * 64 + j * 16 + m16;
                    bv[j] = *(const short8*)&Bs[brow * 64 + (k8 ^ (brow & 7)) * 8];
                }
#pragma unroll
                for (int i = 0; i < 2; ++i)
#pragma unroll
                    for (int j = 0; j < 4; ++j)
                        acc[i][j] = __builtin_amdgcn_mfma_f32_16x16x32_bf16(av[i], bv[j], acc[i][j], 0, 0, 0);
                if (wc == 0) {
                    int lrow = 128 + m16;
                    short8 wv = *(const short8*)&Bs[lrow * 64 + (k8 ^ (lrow & 7)) * 8];
                    acc16[0] = __builtin_amdgcn_mfma_f32_16x16x32_bf16(av[0], wv, acc16[0], 0, 0, 0);
                    acc16[1] = __builtin_amdgcn_mfma_f32_16x16x32_bf16(av[1], wv, acc16[1], 0, 0, 0);
                }
            }
            __syncthreads();
        }

        // logits -> LDS
        if (wc == 0) {
#pragma unroll
            for (int i = 0; i < 2; ++i)
#pragma unroll
                for (int r = 0; r < 4; ++r)
                    logitS[(wr * 32 + i * 16 + quad * 4 + r) * 17 + m16] = acc16[i][r];
        }
        __syncthreads();

        // per-row softmax-cumsum + dist; stage dt for epilogue
        if (tid < 64) {
            int m = m0 + tid;
            float dt = a.tme[(size_t)m * T + t];
            dts[tid] = dt;
            float z[16];
#pragma unroll
            for (int n = 0; n < 16; ++n) z[n] = logitS[tid * 17 + n] + a.bias16[n] + dt * a.wrow16[n];
            float mx = z[0];
#pragma unroll
            for (int j = 1; j < L; ++j) mx = fmaxf(mx, z[j]);
            float e[L], s = 0.f;
#pragma unroll
            for (int j = 0; j < L; ++j) { e[j] = expf(z[j] - mx); s += e[j]; }
            float run = 0.f, fsum = 0.f;
#pragma unroll
            for (int j = 0; j < L; ++j) { run += e[j]; float fmv = run / s; fmimS[tid * 16 + j] = fmv; fsum += fmv; }
            mx = z[L];
#pragma unroll
            for (int j = 1; j < L; ++j) mx = fmaxf(mx, z[L + j]);
            s = 0.f;
#pragma unroll
            for (int j = 0; j < L; ++j) { e[j] = expf(z[L + j] - mx); s += e[j]; }
            run = 0.f;
#pragma unroll
            for (int j = L - 1; j >= 0; --j) { run += e[j]; fmimS[tid * 16 + 8 + j] = run / s; }
            if (nt == 0) {
                float d = 1.0f - fsum / (float)L;
                a.dist_out[(size_t)t * B + m] = d;
                if (t >= T - KW) a.tmp_ds[(size_t)(t - (T - KW)) * B + m] = d;
            }
        }
        __syncthreads();

        // gates + cell update (c in registers); h -> LDS stage
#pragma unroll
        for (int i = 0; i < 2; ++i) {
#pragma unroll
            for (int r = 0; r < 4; ++r) {
                int rl = wr * 32 + i * 16 + quad * 4 + r;
                int m = m0 + rl;
                float dt = dts[rl];
                float fmv = fmimS[rl * 16 + lidx];
                float imv = fmimS[rl * 16 + 8 + lidx];
                float fg = sigmoidf_(acc[i][0][r] + bj[0] + dt * wj[0]);
                float ig = sigmoidf_(acc[i][1][r] + bj[1] + dt * wj[1]);
                float og = sigmoidf_(acc[i][2][r] + bj[2] + dt * wj[2]);
                float ci = tanhf(acc[i][3][r] + bj[3] + dt * wj[3]);
                float ov = fmv * imv;
                float cl = creg[i][r];
                float cn = ov * (fg * cl + ig * ci) + (fmv - ov) * cl + (imv - ov) * ci;
                float hn = og * tanhf(cn);
                creg[i][r] = cn;
                __hip_bfloat16 hb = __float2bfloat16(hn);
                hstageS[rl * 32 + (wc * 16 + m16)] = *(unsigned short*)&hb;
                if (t >= T - KW) a.tmp_h[((size_t)(t - (T - KW)) * B + m) * H + hcol] = hb;
            }
        }
        __syncthreads();

        // pack h pairs -> agent-scope atomic dword stores (device-coherent)
        {
            const unsigned* hs32 = (const unsigned*)hstageS;
#pragma unroll
            for (int wds = 0; wds < 4; ++wds) {
                int wi = wds * 256 + tid;
                int row = wi >> 4, cp = wi & 15;
                unsigned v = hs32[row * 16 + cp];
                __hip_atomic_store(hout32 + (size_t)(m0 + row) * (H / 2) + nt * 16 + cp, v,
                                   __ATOMIC_RELAXED, __HIP_MEMORY_SCOPE_AGENT);
            }
        }

        if (t != T - 1) gridbar(leaf, master, genp, mt, (unsigned)t);
    }
}

// ---------- post ----------
__global__ __launch_bounds__(128) void post_local(
    const __hip_bfloat16* __restrict__ tmp_h, const float* __restrict__ tmp_dis,
    float* __restrict__ mean_h, __hip_bfloat16* __restrict__ Ahk)
{
    const int b = blockIdx.x;
    const int tid = threadIdx.x;
    __shared__ float ld[KW];
    if (tid == 0) {
        float cd[KW];
        float run = 0.f;
        for (int k = 0; k < KW; ++k) { run += tmp_dis[(size_t)k * B + b]; cd[k] = run; }
        float mx = cd[0];
        for (int k = 1; k < KW; ++k) mx = fmaxf(mx, cd[k]);
        float s = 0.f;
        for (int k = 0; k < KW; ++k) { cd[k] = expf(cd[k] - mx); s += cd[k]; }
        for (int k = 0; k < KW; ++k) ld[k] = cd[k] / s;
    }
    __syncthreads();
    float ldr[KW];
#pragma unroll
    for (int k = 0; k < KW; ++k) ldr[k] = ld[k];
    for (int h = tid; h < H; h += 128) {
        float s = 0.f;
#pragma unroll
        for (int k = 0; k < KW; ++k) {
            float v = __bfloat162float(tmp_h[((size_t)k * B + b) * H + h]) * ldr[k];
            s += v;
            Ahk[(size_t)b * RC + h * KW + k] = __float2bfloat16(v);
        }
        mean_h[(size_t)b * H + h] = s * (1.0f / KW);
    }
}

__global__ void theme1_k(const float* __restrict__ mean_h, const float* __restrict__ Ws,
                         const float* __restrict__ bs, float* __restrict__ t1)
{
    int idx = blockIdx.x * blockDim.x + threadIdx.x;
    if (idx >= B * HS) return;
    int b = idx / HS, j = idx % HS;
    float s = bs[j];
    const float* mh = mean_h + (size_t)b * H;
    for (int h = 0; h < H; ++h) s += mh[h] * Ws[(size_t)h * HS + j];
    t1[idx] = fmaxf(s, 0.f);
}

__global__ void theme2_k(const float* __restrict__ t1, const float* __restrict__ Wrs,
                         const float* __restrict__ brs, float* __restrict__ theme)
{
    int idx = blockIdx.x * blockDim.x + threadIdx.x;
    if (idx >= B * H) return;
    int b = idx / H, o = idx % H;
    float s = brs[o];
    const float* tv = t1 + (size_t)b * HS;
    for (int j = 0; j < HS; ++j) s += tv[j] * Wrs[(size_t)j * H + o];
    theme[idx] = sigmoidf_(s);
}

__global__ __launch_bounds__(256) void conv_split(
    const __hip_bfloat16* __restrict__ Ahk, const __hip_bfloat16* __restrict__ CWb,
    float* __restrict__ Pbuf)
{
    __shared__ __align__(16) unsigned short As2[128 * 64];
    __shared__ __align__(16) unsigned short Bs2[128 * 64];
    const int tid = threadIdx.x;
    const int wave = tid >> 6;
    const int wr = wave >> 1, wc = wave & 1;
    const int quad = (tid & 63) >> 4, m16 = tid & 15;
    const int n0 = blockIdx.x * 128, m0 = blockIdx.y * 128;
    const int ksb = blockIdx.z * (RC / KS);

    f32x4 acc[4][4] = {};
    for (int k0 = 0; k0 < RC / KS; k0 += 64) {
#pragma unroll
        for (int p = 0; p < 4; ++p) {
            int o = p * 4096 + tid * 16;
            int row = o >> 7, slot = (o >> 4) & 7;
            int kg = ksb + k0 + (slot ^ (row & 7)) * 8;
            gl_lds16((const unsigned short*)Ahk + (size_t)(m0 + row) * RC + kg, (char*)As2 + o);
            gl_lds16((const unsigned short*)CWb + (size_t)(n0 + row) * RC + kg, (char*)Bs2 + o);
        }
        __syncthreads();
#pragma unroll
        for (int c2 = 0; c2 < 2; ++c2) {
            const int k8 = c2 * 4 + quad;
            short8 av[4], bv[4];
#pragma unroll
            for (int i = 0; i < 4; ++i) {
                int arow = wr * 64 + i * 16 + m16;
                av[i] = *(const short8*)&As2[arow * 64 + (k8 ^ (arow & 7)) * 8];
            }
#pragma unroll
            for (int j = 0; j < 4; ++j) {
                int brow = wc * 64 + j * 16 + m16;
                bv[j] = *(const short8*)&Bs2[brow * 64 + (k8 ^ (brow & 7)) * 8];
            }
#pragma unroll
            for (int i = 0; i < 4; ++i)
#pragma unroll
                for (int j = 0; j < 4; ++j)
                    acc[i][j] = __builtin_amdgcn_mfma_f32_16x16x32_bf16(av[i], bv[j], acc[i][j], 0, 0, 0);
        }
        __syncthreads();
    }
    float* P = Pbuf + (size_t)blockIdx.z * B * H;
#pragma unroll
    for (int j = 0; j < 4; ++j) {
        const int col = n0 + wc * 64 + j * 16 + m16;
#pragma unroll
        for (int i = 0; i < 4; ++i) {
            const int rb = m0 + wr * 64 + i * 16 + quad * 4;
#pragma unroll
            for (int r = 0; r < 4; ++r)
                P[(size_t)(rb + r) * H + col] = acc[i][j][r];
        }
    }
}

__global__ void conv_reduce(const float* __restrict__ Pbuf, const float* __restrict__ conv_b,
                            const float* __restrict__ theme, float* __restrict__ out0)
{
    int i = blockIdx.x * blockDim.x + threadIdx.x;
    if (i >= B * H) return;
    float s = conv_b[i & (H - 1)];
#pragma unroll
    for (int ks = 0; ks < KS; ++ks) s += Pbuf[(size_t)ks * B * H + i];
    out0[i] = theme[i] * s;
}

} // namespace

extern "C" void kernel_launch(void* const* d_in, const int* in_sizes, int n_in,
                              void* d_out, int out_size, void* d_ws, size_t ws_size,
                              hipStream_t stream)
{
    (void)in_sizes; (void)n_in; (void)out_size; (void)ws_size;
    const float* x      = (const float*)d_in[0];
    const float* tme    = (const float*)d_in[1];
    const float* Wk     = (const float*)d_in[2];
    const float* bk     = (const float*)d_in[3];
    const float* Wr     = (const float*)d_in[4];
    const float* br     = (const float*)d_in[5];
    const float* Ws     = (const float*)d_in[6];
    const float* bs     = (const float*)d_in[7];
    const float* Wrs    = (const float*)d_in[8];
    const float* brs    = (const float*)d_in[9];
    const float* conv_w = (const float*)d_in[10];
    const float* conv_b = (const float*)d_in[11];

    float* out0 = (float*)d_out;
    float* dist_out = out0 + (size_t)B * H;

    // workspace carve (~162 MB)
    char* w = (char*)d_ws;
    __hip_bfloat16* WgT  = (__hip_bfloat16*)w; w += (size_t)16 * NROW * KIN * 2;
    __hip_bfloat16* xb   = (__hip_bfloat16*)w; w += (size_t)B * T * F * 2;
    __hip_bfloat16* CWb  = (__hip_bfloat16*)w; w += (size_t)H * RC * 2;
    __hip_bfloat16* Ahk  = (__hip_bfloat16*)w; w += (size_t)B * RC * 2;
    __hip_bfloat16* hb0  = (__hip_bfloat16*)w; w += (size_t)B * H * 2;
    __hip_bfloat16* hb1  = (__hip_bfloat16*)w; w += (size_t)B * H * 2;
    __hip_bfloat16* tmp_h = (__hip_bfloat16*)w; w += (size_t)KW * B * H * 2;
    float* biasg  = (float*)w; w += (size_t)NG * 4;
    float* wrowg  = (float*)w; w += (size_t)NG * 4;
    float* bias16 = (float*)w; w += 64;
    float* wrow16 = (float*)w; w += 64;
    float* tmp_ds = (float*)w; w += (size_t)KW * B * 4;
    float* mean_h = (float*)w; w += (size_t)B * H * 4;
    float* t1     = (float*)w; w += (size_t)B * HS * 4;
    float* theme  = (float*)w; w += (size_t)B * H * 4;
    float* Pbuf   = (float*)w; w += (size_t)KS * B * H * 4;
    unsigned* bar = (unsigned*)w; w += 4096;  // leaf[0..511] | master@512 | gen@544

    hipMemsetAsync(hb0, 0, (size_t)B * H * sizeof(__hip_bfloat16), stream);
    hipMemsetAsync(bar, 0, 4096, stream);

    prep_wgt<<<dim3(NG / 64, KIN / 64), 256, 0, stream>>>(Wk, Wr, WgT);
    prep_w16rep<<<(16 * 16 * KIN + 255) / 256, 256, 0, stream>>>(Wk, Wr, WgT);
    prep_small<<<1, 256, 0, stream>>>(Wk, bk, Wr, br, biasg, wrowg, bias16, wrow16);
    convert_x<<<((B * T * F / 4) + 255) / 256, 256, 0, stream>>>(x, xb);
    prep_convw<<<((H * RC / 4) + 255) / 256, 256, 0, stream>>>(conv_w, CWb);

    {
        StepArgs sa;
        sa.xb = xb; sa.h0 = hb0; sa.h1 = hb1; sa.WgT = WgT;
        sa.biasg = biasg; sa.wrowg = wrowg; sa.bias16 = bias16; sa.wrow16 = wrow16;
        sa.tme = tme; sa.tmp_h = tmp_h; sa.tmp_ds = tmp_ds; sa.dist_out = dist_out;
        sa.bar = bar;
        persistent_step<<<512, 256, 0, stream>>>(sa);
    }

    post_local<<<B, 128, 0, stream>>>(tmp_h, tmp_ds, mean_h, Ahk);
    theme1_k<<<(B * HS + 255) / 256, 256, 0, stream>>>(mean_h, Ws, bs, t1);
    theme2_k<<<(B * H + 255) / 256, 256, 0, stream>>>(t1, Wrs, brs, theme);
    conv_split<<<dim3(H / 128, B / 128, KS), 256, 0, stream>>>(Ahk, CWb, Pbuf);
    conv_reduce<<<(B * H + 255) / 256, 256, 0, stream>>>(Pbuf, conv_b, theme, out0);
}

// Round 9
// 2417.194 us; speedup vs baseline: 2.8073x; 1.1930x over previous
//
#include <hip/hip_runtime.h>
#include <hip/hip_bf16.h>
#include <cstddef>
#include <cstdint>

namespace {

constexpr int B = 2048, T = 128, F = 128, H = 512, L = 8, KW = 10;
constexpr int GATES = 2064;
constexpr int NG = 2048;    // gate columns (permuted)
constexpr int KIN = 640;    // F + H
constexpr int HS = 85;      // H // 6
constexpr int RC = H * KW;  // 5120
constexpr int KS = 8;       // conv split-K slices
constexpr int NROW = 144;   // Bs rows per tile: 128 gates + 16 logit cols

typedef __attribute__((ext_vector_type(8))) short short8;
typedef __attribute__((ext_vector_type(4))) float f32x4;
typedef unsigned long long ull;

__device__ __forceinline__ float fsigmoid_(float x) {
    return __builtin_amdgcn_rcpf(1.0f + __expf(-x));
}
__device__ __forceinline__ float ftanh_(float x) {
    return 1.0f - 2.0f * __builtin_amdgcn_rcpf(1.0f + __expf(2.0f * x));
}

__device__ __forceinline__ void gl_lds16(const void* g, void* l) {
    __builtin_amdgcn_global_load_lds(
        (const __attribute__((address_space(1))) unsigned int*)g,
        (__attribute__((address_space(3))) unsigned int*)l,
        16, 0, 0);
}

__device__ __forceinline__ ull h_atomic_load(const void* p) {
    return __hip_atomic_load((const ull*)p, __ATOMIC_RELAXED, __HIP_MEMORY_SCOPE_AGENT);
}

// ---------- prep (unchanged from R8) ----------
__global__ __launch_bounds__(256) void prep_wgt(
    const float* __restrict__ Wk, const float* __restrict__ Wr,
    __hip_bfloat16* __restrict__ WgT)
{
    __shared__ float tile[64 * 65];
    const int tid = threadIdx.x;
    const int c0 = blockIdx.x * 64, k0 = blockIdx.y * 64;
#pragma unroll
    for (int rep = 0; rep < 16; ++rep) {
        int e = rep * 256 + tid;
        int kl = e >> 6, cl = e & 63;
        int col = c0 + cl;
        int nt = col >> 7, cc = col & 127;
        int n = 16 + ((cc >> 4) & 3) * 512 + nt * 32 + ((cc >> 6) & 1) * 16 + (cc & 15);
        int k = k0 + kl;
        tile[kl * 65 + cl] = (k < F) ? Wk[(size_t)k * GATES + n] : Wr[(size_t)(k - F) * GATES + n];
    }
    __syncthreads();
    const int cl = tid >> 2, q = tid & 3;
    unsigned short buf[16];
#pragma unroll
    for (int i = 0; i < 16; ++i) {
        float f = tile[(q * 16 + i) * 65 + cl];
        __hip_bfloat16 bv = __float2bfloat16(f);
        buf[i] = *(unsigned short*)&bv;
    }
    int col = c0 + cl;
    int nt = col >> 7, rin = col & 127;
    unsigned short* dst = (unsigned short*)WgT + (size_t)nt * NROW * KIN + (size_t)rin * KIN + k0 + q * 16;
    *(short8*)dst = *(short8*)&buf[0];
    *(short8*)(dst + 8) = *(short8*)&buf[8];
}

__global__ void prep_w16rep(const float* __restrict__ Wk, const float* __restrict__ Wr,
                            __hip_bfloat16* __restrict__ WgT)
{
    int idx = blockIdx.x * blockDim.x + threadIdx.x;
    if (idx >= 16 * 16 * KIN) return;
    int nt = idx / (16 * KIN);
    int rem = idx % (16 * KIN);
    int n = rem / KIN, k = rem % KIN;
    float v = (k < F) ? Wk[(size_t)k * GATES + n] : Wr[(size_t)(k - F) * GATES + n];
    WgT[(size_t)nt * NROW * KIN + (size_t)(128 + n) * KIN + k] = __float2bfloat16(v);
}

__global__ void prep_small(const float* __restrict__ Wk, const float* __restrict__ bk,
                           const float* __restrict__ Wr, const float* __restrict__ br,
                           float* __restrict__ biasg, float* __restrict__ wrowg,
                           float* __restrict__ bias16, float* __restrict__ wrow16)
{
    const int total = 2 * NG + 32;
    for (int idx = threadIdx.x; idx < total; idx += 256) {
        if (idx < NG) {
            int col = idx;
            int nt = col >> 7, cc = col & 127;
            int n = 16 + ((cc >> 4) & 3) * 512 + nt * 32 + ((cc >> 6) & 1) * 16 + (cc & 15);
            biasg[col] = bk[n] + br[n];
        } else if (idx < 2 * NG) {
            int col = idx - NG;
            int nt = col >> 7, cc = col & 127;
            int n = 16 + ((cc >> 4) & 3) * 512 + nt * 32 + ((cc >> 6) & 1) * 16 + (cc & 15);
            wrowg[col] = Wk[(size_t)F * GATES + n] + Wr[(size_t)H * GATES + n];
        } else if (idx < 2 * NG + 16) {
            int n = idx - 2 * NG;
            bias16[n] = bk[n] + br[n];
        } else {
            int n = idx - 2 * NG - 16;
            wrow16[n] = Wk[(size_t)F * GATES + n] + Wr[(size_t)H * GATES + n];
        }
    }
}

__global__ void convert_x(const float* __restrict__ x, __hip_bfloat16* __restrict__ xb) {
    int i = blockIdx.x * blockDim.x + threadIdx.x;
    size_t o = (size_t)i * 4;
    if (o >= (size_t)B * T * F) return;
    float4 v = *(const float4*)(x + o);
    xb[o + 0] = __float2bfloat16(v.x);
    xb[o + 1] = __float2bfloat16(v.y);
    xb[o + 2] = __float2bfloat16(v.z);
    xb[o + 3] = __float2bfloat16(v.w);
}

__global__ void prep_convw(const float* __restrict__ conv_w, __hip_bfloat16* __restrict__ CWb) {
    int i = blockIdx.x * blockDim.x + threadIdx.x;
    if (i >= H * RC / 4) return;
    size_t o = (size_t)i * 4;
    float4 v = *(const float4*)(conv_w + o);
    CWb[o + 0] = __float2bfloat16(v.x);
    CWb[o + 1] = __float2bfloat16(v.y);
    CWb[o + 2] = __float2bfloat16(v.z);
    CWb[o + 3] = __float2bfloat16(v.w);
}

// ---------- persistent fused step ----------
struct StepArgs {
    const __hip_bfloat16* xb;
    __hip_bfloat16* h0;
    __hip_bfloat16* h1;
    const __hip_bfloat16* WgT;
    const float* biasg;
    const float* wrowg;
    const float* bias16;
    const float* wrow16;
    const float* tme;
    __hip_bfloat16* tmp_h;
    float* tmp_ds;
    float* dist_out;
    unsigned* bar;  // leaf[16*16] | master @512 | gen @544
};

// 256 blocks (16 mt x 16 nt, XCD-swizzled), 512 threads. M-tile 128, N-tile
// 128(+16 logit rows), BK 32, fully unrolled 20-iter k-loop, LDS double-buffer.
// cell state in registers; h exchanged via relaxed agent atomics (R7-verified).
__global__ __launch_bounds__(512, 2) void persistent_step(StepArgs a)
{
    // abuf0 @0 (8K) | abuf1 @8192 | bbuf0 @16384 (9216) | bbuf1 @25600 -> 34816 B
    __shared__ __align__(16) char smem[34816];
    // epilogue aliases (all staging except bbuf1 dead by then):
    float* logitS = (float*)smem;                              // 128*17*4 = 8704
    float* fmimS = (float*)(smem + 8704);                      // 8192
    unsigned short* hstageS = (unsigned short*)(smem + 16896); // 8192
    float* dts = (float*)(smem + 25088);                       // 512

    const int tid = threadIdx.x;
    const int wave = tid >> 6;
    const int wr = wave >> 1, wc = wave & 1;   // wr 0..3, wc 0..1
    const int quad = (tid & 63) >> 4, m16 = tid & 15;
    const int l = blockIdx.x;
    const int nt = ((l & 7) << 1) | ((l >> 3) & 1);  // same-nt -> same XCD
    const int mt = l >> 4;
    const int m0 = mt * 128;

    unsigned* leaf = a.bar;
    unsigned* master = a.bar + 512;
    unsigned* genp = a.bar + 544;

    // ---- per-thread staging geometry (A tile 128x32 bf16 = 8 KB; 16 B/thread)
    const int o0 = tid * 16;
    const int arow = o0 >> 6;                       // 64 B per row
    const int asl = ((((o0 >> 4) & 3) ^ ((arow >> 1) & 3)) << 3);  // k-elt offset
    // x/h byte bases for this thread's chunk
    const char* xbT = (const char*)a.xb + (size_t)(m0 + arow) * (T * F * 2) + asl * 2;
    const size_t hbyte = (size_t)(m0 + arow) * (H * 2) + asl * 2;
    // Bs: 144x32 bf16 = 9216 B; p0 = tid*16 (all), p1 = 8192 + tid*16 (tid<64)
    const unsigned short* wgt_tile = (const unsigned short*)a.WgT + (size_t)nt * NROW * KIN;
    const int brow0 = o0 >> 6;
    const int bsl0 = ((((o0 >> 4) & 3) ^ ((brow0 >> 1) & 3)) << 3);
    const char* bsT0 = (const char*)(wgt_tile + (size_t)brow0 * KIN + bsl0);
    const int ob1 = 8192 + tid * 16;
    const int brow1 = ob1 >> 6;
    const int bsl1 = ((((ob1 >> 4) & 3) ^ ((brow1 >> 1) & 3)) << 3);
    const char* bsT1 = (const char*)(wgt_tile + (size_t)brow1 * KIN + bsl1);
    const bool bv1 = (tid < 64);

    // t-invariant epilogue constants
    const int hcol = nt * 32 + wc * 16 + m16;
    const int lidx = hcol >> 6;
    float bj[4], wj[4];
#pragma unroll
    for (int j = 0; j < 4; ++j) {
        int col = nt * 128 + wc * 64 + j * 16 + m16;
        bj[j] = a.biasg[col];
        wj[j] = a.wrowg[col];
    }
    float b16r[16], w16r[16];
#pragma unroll
    for (int n = 0; n < 16; ++n) { b16r[n] = a.bias16[n]; w16r[n] = a.wrow16[n]; }

    // frag-read addresses (two buffers each)
    const unsigned short* Abase = (const unsigned short*)smem;
    const unsigned short* Bbase = (const unsigned short*)(smem + 16384);

    float creg[2][4] = {};
    ull areg[2][2];

    // pre-issue t=0 iter0 staging + x reg preloads for iters 1,2
    {
        gl_lds16(xbT, smem + o0);
        gl_lds16(bsT0, smem + 16384 + o0);
        if (bv1) gl_lds16(bsT1, smem + 16384 + ob1);
        areg[1][0] = *(const ull*)(xbT + 64);  areg[1][1] = *(const ull*)(xbT + 72);
        areg[0][0] = *(const ull*)(xbT + 128); areg[0][1] = *(const ull*)(xbT + 136);
    }

#pragma unroll 1
    for (int t = 0; t < T; ++t) {
        const char* xt = xbT + (size_t)t * 256;
        const char* hs = (const char*)((t & 1) ? a.h1 : a.h0) + hbyte;
        unsigned* hout32 = (unsigned*)((t & 1) ? a.h0 : a.h1);

        f32x4 acc[2][4] = {};
        f32x4 acc16[2] = {};

#pragma unroll
        for (int ki = 0; ki < 20; ++ki) {
            __syncthreads();
            const int nxt = ki + 1;
            if (nxt < 20) {
                // stage A(nxt) from regs (iters 1..19; x preloaded / h pipelined)
                char* adst = smem + (nxt & 1) * 8192 + o0;
                *(ull*)adst = areg[nxt & 1][0];
                *(ull*)(adst + 8) = areg[nxt & 1][1];
                // stage B(nxt) via DMA
                char* bdst = smem + 16384 + (nxt & 1) * 9216;
                gl_lds16(bsT0 + nxt * 64, bdst + o0);
                if (bv1) gl_lds16(bsT1 + nxt * 64, bdst + ob1);
                // reload areg set for iter ki+3
                const int fut = ki + 3;
                if (fut < 20) {
                    if (fut <= 3) {
                        areg[fut & 1][0] = *(const ull*)(xt + fut * 64);
                        areg[fut & 1][1] = *(const ull*)(xt + fut * 64 + 8);
                    } else {
                        areg[fut & 1][0] = h_atomic_load(hs + fut * 64 - 256);
                        areg[fut & 1][1] = h_atomic_load(hs + fut * 64 - 248);
                    }
                }
            }
            // compute iter ki from buf ki&1
            const unsigned short* A = Abase + (ki & 1) * 4096;
            const unsigned short* Bb = Bbase + (ki & 1) * 4608;
            short8 av[2], bv[4];
#pragma unroll
            for (int i = 0; i < 2; ++i) {
                int ar = wr * 32 + i * 16 + m16;
                av[i] = *(const short8*)&A[ar * 32 + ((quad ^ ((ar >> 1) & 3)) << 3)];
            }
#pragma unroll
            for (int j = 0; j < 4; ++j) {
                int br = wc * 64 + j * 16 + m16;
                bv[j] = *(const short8*)&Bb[br * 32 + ((quad ^ ((br >> 1) & 3)) << 3)];
            }
#pragma unroll
            for (int i = 0; i < 2; ++i)
#pragma unroll
                for (int j = 0; j < 4; ++j)
                    acc[i][j] = __builtin_amdgcn_mfma_f32_16x16x32_bf16(av[i], bv[j], acc[i][j], 0, 0, 0);
            if (wc == 0) {
                int lr = 128 + m16;
                short8 wv = *(const short8*)&Bb[lr * 32 + ((quad ^ ((lr >> 1) & 3)) << 3)];
                acc16[0] = __builtin_amdgcn_mfma_f32_16x16x32_bf16(av[0], wv, acc16[0], 0, 0, 0);
                acc16[1] = __builtin_amdgcn_mfma_f32_16x16x32_bf16(av[1], wv, acc16[1], 0, 0, 0);
            }
        }
        __syncthreads();  // all frag reads done before scratch aliasing

        // logits -> LDS (wc==0 waves: wr 0..3 cover 128 rows)
        if (wc == 0) {
#pragma unroll
            for (int i = 0; i < 2; ++i)
#pragma unroll
                for (int r = 0; r < 4; ++r)
                    logitS[(wr * 32 + i * 16 + quad * 4 + r) * 17 + m16] = acc16[i][r];
        }
        __syncthreads();

        // per-row softmax-cumsum + dist (128 rows)
        if (tid < 128) {
            int m = m0 + tid;
            float dt = a.tme[(size_t)m * T + t];
            dts[tid] = dt;
            float z[16];
#pragma unroll
            for (int n = 0; n < 16; ++n) z[n] = logitS[tid * 17 + n] + b16r[n] + dt * w16r[n];
            float mx = z[0];
#pragma unroll
            for (int j = 1; j < L; ++j) mx = fmaxf(mx, z[j]);
            float e[L], s = 0.f;
#pragma unroll
            for (int j = 0; j < L; ++j) { e[j] = __expf(z[j] - mx); s += e[j]; }
            float run = 0.f, fsum = 0.f;
#pragma unroll
            for (int j = 0; j < L; ++j) { run += e[j]; float fmv = run / s; fmimS[tid * 16 + j] = fmv; fsum += fmv; }
            mx = z[L];
#pragma unroll
            for (int j = 1; j < L; ++j) mx = fmaxf(mx, z[L + j]);
            s = 0.f;
#pragma unroll
            for (int j = 0; j < L; ++j) { e[j] = __expf(z[L + j] - mx); s += e[j]; }
            run = 0.f;
#pragma unroll
            for (int j = L - 1; j >= 0; --j) { run += e[j]; fmimS[tid * 16 + 8 + j] = run / s; }
            if (nt == 0) {
                float d = 1.0f - fsum / (float)L;
                a.dist_out[(size_t)t * B + m] = d;
                if (t >= T - KW) a.tmp_ds[(size_t)(t - (T - KW)) * B + m] = d;
            }
        }
        __syncthreads();

        // gates + cell update (c in regs); h -> LDS stage
#pragma unroll
        for (int i = 0; i < 2; ++i) {
#pragma unroll
            for (int r = 0; r < 4; ++r) {
                int rl = wr * 32 + i * 16 + quad * 4 + r;
                int m = m0 + rl;
                float dt = dts[rl];
                float fmv = fmimS[rl * 16 + lidx];
                float imv = fmimS[rl * 16 + 8 + lidx];
                float fg = fsigmoid_(acc[i][0][r] + bj[0] + dt * wj[0]);
                float ig = fsigmoid_(acc[i][1][r] + bj[1] + dt * wj[1]);
                float og = fsigmoid_(acc[i][2][r] + bj[2] + dt * wj[2]);
                float ci = ftanh_(acc[i][3][r] + bj[3] + dt * wj[3]);
                float ov = fmv * imv;
                float cl = creg[i][r];
                float cn = ov * (fg * cl + ig * ci) + (fmv - ov) * cl + (imv - ov) * ci;
                float hn = og * ftanh_(cn);
                creg[i][r] = cn;
                __hip_bfloat16 hb = __float2bfloat16(hn);
                hstageS[rl * 32 + (wc * 16 + m16)] = *(unsigned short*)&hb;
                if (t >= T - KW) a.tmp_h[((size_t)(t - (T - KW)) * B + m) * H + hcol] = hb;
            }
        }
        __syncthreads();

        // pack h pairs -> agent-scope atomic dword stores
        {
            const unsigned* hs32 = (const unsigned*)hstageS;
#pragma unroll
            for (int wds = 0; wds < 4; ++wds) {
                int wi = wds * 512 + tid;
                int row = wi >> 4, cp = wi & 15;
                unsigned v = hs32[row * 16 + cp];
                __hip_atomic_store(hout32 + (size_t)(m0 + row) * (H / 2) + nt * 16 + cp, v,
                                   __ATOMIC_RELAXED, __HIP_MEMORY_SCOPE_AGENT);
            }
        }

        __syncthreads();  // pack reads done + stores drained (vmcnt0)
        if (t != T - 1) {
            // pre-issue next step's iter0 staging + x preloads (fly during spin)
            const char* xn = xbT + (size_t)(t + 1) * 256;
            gl_lds16(xn, smem + o0);
            gl_lds16(bsT0, smem + 16384 + o0);
            if (bv1) gl_lds16(bsT1, smem + 16384 + ob1);
            areg[1][0] = *(const ull*)(xn + 64);  areg[1][1] = *(const ull*)(xn + 72);
            areg[0][0] = *(const ull*)(xn + 128); areg[0][1] = *(const ull*)(xn + 136);
            if (tid == 0) {
                unsigned old = __hip_atomic_fetch_add(&leaf[mt * 16], 1u,
                                                      __ATOMIC_RELAXED, __HIP_MEMORY_SCOPE_AGENT);
                if (((old + 1u) & 15u) == 0u) {
                    unsigned mo = __hip_atomic_fetch_add(master, 1u,
                                                         __ATOMIC_RELAXED, __HIP_MEMORY_SCOPE_AGENT);
                    if (((mo + 1u) & 15u) == 0u)
                        __hip_atomic_fetch_add(genp, 1u, __ATOMIC_RELAXED, __HIP_MEMORY_SCOPE_AGENT);
                }
                for (int it = 0; it < (1 << 22); ++it) {
                    if (__hip_atomic_load(genp, __ATOMIC_RELAXED, __HIP_MEMORY_SCOPE_AGENT) > (unsigned)t) break;
                    __builtin_amdgcn_s_sleep(4);
                }
            }
            __syncthreads();
        }
    }
}

// ---------- post (unchanged from R8) ----------
__global__ __launch_bounds__(128) void post_local(
    const __hip_bfloat16* __restrict__ tmp_h, const float* __restrict__ tmp_dis,
    float* __restrict__ mean_h, __hip_bfloat16* __restrict__ Ahk)
{
    const int b = blockIdx.x;
    const int tid = threadIdx.x;
    __shared__ float ld[KW];
    if (tid == 0) {
        float cd[KW];
        float run = 0.f;
        for (int k = 0; k < KW; ++k) { run += tmp_dis[(size_t)k * B + b]; cd[k] = run; }
        float mx = cd[0];
        for (int k = 1; k < KW; ++k) mx = fmaxf(mx, cd[k]);
        float s = 0.f;
        for (int k = 0; k < KW; ++k) { cd[k] = expf(cd[k] - mx); s += cd[k]; }
        for (int k = 0; k < KW; ++k) ld[k] = cd[k] / s;
    }
    __syncthreads();
    float ldr[KW];
#pragma unroll
    for (int k = 0; k < KW; ++k) ldr[k] = ld[k];
    for (int h = tid; h < H; h += 128) {
        float s = 0.f;
#pragma unroll
        for (int k = 0; k < KW; ++k) {
            float v = __bfloat162float(tmp_h[((size_t)k * B + b) * H + h]) * ldr[k];
            s += v;
            Ahk[(size_t)b * RC + h * KW + k] = __float2bfloat16(v);
        }
        mean_h[(size_t)b * H + h] = s * (1.0f / KW);
    }
}

__global__ void theme1_k(const float* __restrict__ mean_h, const float* __restrict__ Ws,
                         const float* __restrict__ bs, float* __restrict__ t1)
{
    int idx = blockIdx.x * blockDim.x + threadIdx.x;
    if (idx >= B * HS) return;
    int b = idx / HS, j = idx % HS;
    float s = bs[j];
    const float* mh = mean_h + (size_t)b * H;
    for (int h = 0; h < H; ++h) s += mh[h] * Ws[(size_t)h * HS + j];
    t1[idx] = fmaxf(s, 0.f);
}

__global__ void theme2_k(const float* __restrict__ t1, const float* __restrict__ Wrs,
                         const float* __restrict__ brs, float* __restrict__ theme)
{
    int idx = blockIdx.x * blockDim.x + threadIdx.x;
    if (idx >= B * H) return;
    int b = idx / H, o = idx % H;
    float s = brs[o];
    const float* tv = t1 + (size_t)b * HS;
    for (int j = 0; j < HS; ++j) s += tv[j] * Wrs[(size_t)j * H + o];
    theme[idx] = 1.0f / (1.0f + expf(-s));
}

__global__ __launch_bounds__(256) void conv_split(
    const __hip_bfloat16* __restrict__ Ahk, const __hip_bfloat16* __restrict__ CWb,
    float* __restrict__ Pbuf)
{
    __shared__ __align__(16) unsigned short As2[128 * 64];
    __shared__ __align__(16) unsigned short Bs2[128 * 64];
    const int tid = threadIdx.x;
    const int wave = tid >> 6;
    const int wr = wave >> 1, wc = wave & 1;
    const int quad = (tid & 63) >> 4, m16 = tid & 15;
    const int n0 = blockIdx.x * 128, m0 = blockIdx.y * 128;
    const int ksb = blockIdx.z * (RC / KS);

    f32x4 acc[4][4] = {};
    for (int k0 = 0; k0 < RC / KS; k0 += 64) {
#pragma unroll
        for (int p = 0; p < 4; ++p) {
            int o = p * 4096 + tid * 16;
            int row = o >> 7, slot = (o >> 4) & 7;
            int kg = ksb + k0 + (slot ^ (row & 7)) * 8;
            gl_lds16((const unsigned short*)Ahk + (size_t)(m0 + row) * RC + kg, (char*)As2 + o);
            gl_lds16((const unsigned short*)CWb + (size_t)(n0 + row) * RC + kg, (char*)Bs2 + o);
        }
        __syncthreads();
#pragma unroll
        for (int c2 = 0; c2 < 2; ++c2) {
            const int k8 = c2 * 4 + quad;
            short8 av[4], bv[4];
#pragma unroll
            for (int i = 0; i < 4; ++i) {
                int arow = wr * 64 + i * 16 + m16;
                av[i] = *(const short8*)&As2[arow * 64 + (k8 ^ (arow & 7)) * 8];
            }
#pragma unroll
            for (int j = 0; j < 4; ++j) {
                int brow = wc * 64 + j * 16 + m16;
                bv[j] = *(const short8*)&Bs2[brow * 64 + (k8 ^ (brow & 7)) * 8];
            }
#pragma unroll
            for (int i = 0; i < 4; ++i)
#pragma unroll
                for (int j = 0; j < 4; ++j)
                    acc[i][j] = __builtin_amdgcn_mfma_f32_16x16x32_bf16(av[i], bv[j], acc[i][j], 0, 0, 0);
        }
        __syncthreads();
    }
    float* P = Pbuf + (size_t)blockIdx.z * B * H;
#pragma unroll
    for (int j = 0; j < 4; ++j) {
        const int col = n0 + wc * 64 + j * 16 + m16;
#pragma unroll
        for (int i = 0; i < 4; ++i) {
            const int rb = m0 + wr * 64 + i * 16 + quad * 4;
#pragma unroll
            for (int r = 0; r < 4; ++r)
                P[(size_t)(rb + r) * H + col] = acc[i][j][r];
        }
    }
}

__global__ void conv_reduce(const float* __restrict__ Pbuf, const float* __restrict__ conv_b,
                            const float* __restrict__ theme, float* __restrict__ out0)
{
    int i = blockIdx.x * blockDim.x + threadIdx.x;
    if (i >= B * H) return;
    float s = conv_b[i & (H - 1)];
#pragma unroll
    for (int ks = 0; ks < KS; ++ks) s += Pbuf[(size_t)ks * B * H + i];
    out0[i] = theme[i] * s;
}

} // namespace

extern "C" void kernel_launch(void* const* d_in, const int* in_sizes, int n_in,
                              void* d_out, int out_size, void* d_ws, size_t ws_size,
                              hipStream_t stream)
{
    (void)in_sizes; (void)n_in; (void)out_size; (void)ws_size;
    const float* x      = (const float*)d_in[0];
    const float* tme    = (const float*)d_in[1];
    const float* Wk     = (const float*)d_in[2];
    const float* bk     = (const float*)d_in[3];
    const float* Wr     = (const float*)d_in[4];
    const float* br     = (const float*)d_in[5];
    const float* Ws     = (const float*)d_in[6];
    const float* bs     = (const float*)d_in[7];
    const float* Wrs    = (const float*)d_in[8];
    const float* brs    = (const float*)d_in[9];
    const float* conv_w = (const float*)d_in[10];
    const float* conv_b = (const float*)d_in[11];

    float* out0 = (float*)d_out;
    float* dist_out = out0 + (size_t)B * H;

    // workspace carve (~162 MB)
    char* w = (char*)d_ws;
    __hip_bfloat16* WgT  = (__hip_bfloat16*)w; w += (size_t)16 * NROW * KIN * 2;
    __hip_bfloat16* xb   = (__hip_bfloat16*)w; w += (size_t)B * T * F * 2;
    __hip_bfloat16* CWb  = (__hip_bfloat16*)w; w += (size_t)H * RC * 2;
    __hip_bfloat16* Ahk  = (__hip_bfloat16*)w; w += (size_t)B * RC * 2;
    __hip_bfloat16* hb0  = (__hip_bfloat16*)w; w += (size_t)B * H * 2;
    __hip_bfloat16* hb1  = (__hip_bfloat16*)w; w += (size_t)B * H * 2;
    __hip_bfloat16* tmp_h = (__hip_bfloat16*)w; w += (size_t)KW * B * H * 2;
    float* biasg  = (float*)w; w += (size_t)NG * 4;
    float* wrowg  = (float*)w; w += (size_t)NG * 4;
    float* bias16 = (float*)w; w += 64;
    float* wrow16 = (float*)w; w += 64;
    float* tmp_ds = (float*)w; w += (size_t)KW * B * 4;
    float* mean_h = (float*)w; w += (size_t)B * H * 4;
    float* t1     = (float*)w; w += (size_t)B * HS * 4;
    float* theme  = (float*)w; w += (size_t)B * H * 4;
    float* Pbuf   = (float*)w; w += (size_t)KS * B * H * 4;
    unsigned* bar = (unsigned*)w; w += 4096;

    hipMemsetAsync(hb0, 0, (size_t)B * H * sizeof(__hip_bfloat16), stream);
    hipMemsetAsync(bar, 0, 4096, stream);

    prep_wgt<<<dim3(NG / 64, KIN / 64), 256, 0, stream>>>(Wk, Wr, WgT);
    prep_w16rep<<<(16 * 16 * KIN + 255) / 256, 256, 0, stream>>>(Wk, Wr, WgT);
    prep_small<<<1, 256, 0, stream>>>(Wk, bk, Wr, br, biasg, wrowg, bias16, wrow16);
    convert_x<<<((B * T * F / 4) + 255) / 256, 256, 0, stream>>>(x, xb);
    prep_convw<<<((H * RC / 4) + 255) / 256, 256, 0, stream>>>(conv_w, CWb);

    {
        StepArgs sa;
        sa.xb = xb; sa.h0 = hb0; sa.h1 = hb1; sa.WgT = WgT;
        sa.biasg = biasg; sa.wrowg = wrowg; sa.bias16 = bias16; sa.wrow16 = wrow16;
        sa.tme = tme; sa.tmp_h = tmp_h; sa.tmp_ds = tmp_ds; sa.dist_out = dist_out;
        sa.bar = bar;
        persistent_step<<<256, 512, 0, stream>>>(sa);
    }

    post_local<<<B, 128, 0, stream>>>(tmp_h, tmp_ds, mean_h, Ahk);
    theme1_k<<<(B * HS + 255) / 256, 256, 0, stream>>>(mean_h, Ws, bs, t1);
    theme2_k<<<(B * H + 255) / 256, 256, 0, stream>>>(t1, Wrs, brs, theme);
    conv_split<<<dim3(H / 128, B / 128, KS), 256, 0, stream>>>(Ahk, CWb, Pbuf);
    conv_reduce<<<(B * H + 255) / 256, 256, 0, stream>>>(Pbuf, conv_b, theme, out0);
}